// Round 1
// baseline (2119.524 us; speedup 1.0000x reference)
//
#include <hip/hip_runtime.h>
#include <hip/hip_bf16.h>
#include <math.h>

typedef __bf16 bf8_t __attribute__((ext_vector_type(8)));
typedef __bf16 bf4_t __attribute__((ext_vector_type(4)));
typedef float  f4_t  __attribute__((ext_vector_type(4)));

#define AS_G __attribute__((address_space(1)))
#define AS_L __attribute__((address_space(3)))

static __device__ __forceinline__ void gl_lds16(const __bf16* g, __bf16* l) {
    __builtin_amdgcn_global_load_lds((const AS_G void*)g, (AS_L void*)l, 16, 0, 0);
}

// raw barrier with compile-time memory fences on both sides (keeps the
// compiler from hoisting LDS reads / global_load_lds across the barrier,
// without triggering __syncthreads' vmcnt(0) drain)
static __device__ __forceinline__ void phase_bar() {
    asm volatile("" ::: "memory");
    __builtin_amdgcn_s_barrier();
    asm volatile("" ::: "memory");
}

// ---------------------------------------------------------------------------
// 128x128-tile GEMM (unchanged, verified): C[m,n] = sum_k A[m,k]*Bt[n,k]
// ---------------------------------------------------------------------------
enum {
    EPI_NONE = 0,   // store bf16
    EPI_BCOL,       // + aux[col], store bf16
    EPI_BCOL_ELU,   // elu(x+aux[col])+1, store bf16
    EPI_BROW,       // + aux[row], store bf16
    EPI_BROW_ELU,   // elu(x+aux[row])+1, store bf16
    EPI_ZDIV,       // x / aux[row], store bf16
    EPI_BCOL_F32    // + aux[col], store f32
};

template<int EPI>
__global__ __launch_bounds__(256)
void gemm_bt(const __bf16* __restrict__ A, long lda, long zsA,
             const __bf16* __restrict__ Bt, long ldb, long zsB,
             void* __restrict__ Cv, long ldc, long zsC,
             int M, int N, int K,
             const float* __restrict__ aux, long zsAux)
{
    __shared__ __align__(16) __bf16 tA[128 * 32];
    __shared__ __align__(16) __bf16 tB[128 * 32];

    const int tid  = threadIdx.x;
    const int wave = tid >> 6;
    const int lane = tid & 63;
    const int wm   = (wave >> 1) * 64;   // wave m-offset in tile
    const int wn   = (wave & 1) * 64;    // wave n-offset in tile
    const int m0   = blockIdx.y * 128;
    const int n0   = blockIdx.x * 128;
    const long z   = blockIdx.z;

    A  += z * zsA;
    Bt += z * zsB;

    f4_t acc[4][4] = {};

    const int quad = lane >> 4;
    const int l16  = lane & 15;
    const int koff = quad * 8;           // k-offset of this lane's fragment

    for (int k0 = 0; k0 < K; k0 += 32) {
        // stage 128x32 A-tile and B-tile: 512 x 16B chunks each, 2 rounds
        #pragma unroll
        for (int p = 0; p < 2; ++p) {
            const int cb = p * 256 + wave * 64;   // wave-uniform chunk base
            const int c  = cb + lane;             // this lane's chunk
            const int r  = c >> 2;                // tile row (4 chunks = 64B/row)
            const int kc = (c & 3) * 8;           // k element offset
            gl_lds16(A + (long)(m0 + r) * lda + (k0 + kc), tA + cb * 8);
            int rb = n0 + r; rb = rb < N ? rb : N - 1;   // clamp for N edge
            gl_lds16(Bt + (long)rb * ldb + (k0 + kc), tB + cb * 8);
        }
        __syncthreads();

        bf8_t af[4], bfr[4];
        #pragma unroll
        for (int i = 0; i < 4; ++i) {
            af[i]  = *(const bf8_t*)(tA + (wm + i * 16 + l16) * 32 + koff);
            bfr[i] = *(const bf8_t*)(tB + (wn + i * 16 + l16) * 32 + koff);
        }
        #pragma unroll
        for (int i = 0; i < 4; ++i)
            #pragma unroll
            for (int j = 0; j < 4; ++j)
                acc[i][j] = __builtin_amdgcn_mfma_f32_16x16x32_bf16(
                    af[i], bfr[j], acc[i][j], 0, 0, 0);
        __syncthreads();
    }

    // epilogue: C/D layout col=lane&15, row=quad*4+reg (m89/m91-verified)
    const float* auxp = aux + z * zsAux;
    float*  Cf = (float*) Cv + z * zsC;
    __bf16* Cb = (__bf16*)Cv + z * zsC;

    #pragma unroll
    for (int i = 0; i < 4; ++i) {
        const int rbase = m0 + wm + i * 16 + quad * 4;
        #pragma unroll
        for (int j = 0; j < 4; ++j) {
            const int col = n0 + wn + j * 16 + l16;
            if (col >= N) continue;
            float bias_c = 0.f;
            if constexpr (EPI == EPI_BCOL || EPI == EPI_BCOL_ELU || EPI == EPI_BCOL_F32)
                bias_c = auxp[col];
            #pragma unroll
            for (int r = 0; r < 4; ++r) {
                const int row = rbase + r;
                if (row >= M) continue;
                float v = acc[i][j][r];
                if constexpr (EPI == EPI_BCOL || EPI == EPI_BCOL_F32) v += bias_c;
                if constexpr (EPI == EPI_BCOL_ELU) {
                    v += bias_c; v = v >= 0.f ? v + 1.f : __expf(v);
                }
                if constexpr (EPI == EPI_BROW) v += auxp[row];
                if constexpr (EPI == EPI_BROW_ELU) {
                    v += auxp[row]; v = v >= 0.f ? v + 1.f : __expf(v);
                }
                if constexpr (EPI == EPI_ZDIV) v /= auxp[row];
                if constexpr (EPI == EPI_BCOL_F32)
                    Cf[(long)row * ldc + col] = v;
                else
                    Cb[(long)row * ldc + col] = (__bf16)v;
            }
        }
    }
}

// ---------------------------------------------------------------------------
// 256x256-tile, BK=64, 8-wave (2Mx4N), 4-phase/K-tile pipelined GEMM for the
// LM head:  C[m,n] = sum_k A[m,k]*Bt[n,k] + aux[n], fp32 store.
// Requires: M % 256 == 0, K % 64 == 0, K/64 >= 3. N-edge handled by clamping
// B rows on stage + col guard in epilogue.
//
// LDS: per buffer (2) and operand: two 16KB "units" (A split by mq = m-halves
// of the per-wave range; B split by nq = n-halves). XOR swizzle on the
// k-chunk index (col8 ^= rowslot&7) applied on the *global source* address of
// global_load_lds (LDS dest stays linear) and on the ds_read address.
//
// Pipeline (unit staged -> first ds_read):
//   A0[V] @ (V-2,ph3) -> (V,ph1)   B0[V] @ (V-2,ph4) -> (V,ph1)
//   A1[V] @ (V-1,ph1) -> (V,ph3)   B1[V] @ (V-1,ph2) -> (V,ph2)
// Counted waits (per-wave, 2 loads/unit): vmcnt(6) end of ph1 (covers B1[V]),
// vmcnt(8) end of ph4 (covers A0/B0[V+1]). Never drained to 0 in the loop.
// ---------------------------------------------------------------------------
#define READ_AQ(PTR)                                                          \
    _Pragma("unroll")                                                         \
    for (int ii = 0; ii < 4; ++ii) {                                          \
        const int ro = (wr * 64 + ii * 16 + l16) * 64;                        \
        af[ii][0] = *(const bf8_t*)((PTR) + ro + kx0);                        \
        af[ii][1] = *(const bf8_t*)((PTR) + ro + kx1);                        \
    }

#define READ_BQ(PTR, BQ)                                                      \
    _Pragma("unroll")                                                         \
    for (int jj = 0; jj < 2; ++jj) {                                          \
        const int ro = (wc * 32 + jj * 16 + l16) * 64;                        \
        BQ[jj][0] = *(const bf8_t*)((PTR) + ro + kx0);                        \
        BQ[jj][1] = *(const bf8_t*)((PTR) + ro + kx1);                        \
    }

#define MFMA_QUAD(MB, NB, BQ)                                                 \
    _Pragma("unroll")                                                         \
    for (int ii = 0; ii < 4; ++ii) {                                          \
        _Pragma("unroll")                                                     \
        for (int jj = 0; jj < 2; ++jj) {                                      \
            acc[(MB) + ii][(NB) + jj] = __builtin_amdgcn_mfma_f32_16x16x32_bf16( \
                af[ii][0], BQ[jj][0], acc[(MB) + ii][(NB) + jj], 0, 0, 0);    \
            acc[(MB) + ii][(NB) + jj] = __builtin_amdgcn_mfma_f32_16x16x32_bf16( \
                af[ii][1], BQ[jj][1], acc[(MB) + ii][(NB) + jj], 0, 0, 0);    \
        }                                                                     \
    }

__global__ __launch_bounds__(512)
void gemm256_head(const __bf16* __restrict__ A, int lda,
                  const __bf16* __restrict__ Bt, int ldb,
                  float* __restrict__ C, int ldc,
                  int M, int N, int K, const float* __restrict__ aux)
{
    __shared__ __align__(16) __bf16 sA[2][2][8192];   // [buf][mq][16KB unit]
    __shared__ __align__(16) __bf16 sB[2][2][8192];   // [buf][nq][16KB unit]

    const int tid  = threadIdx.x;
    const int wave = tid >> 6;
    const int lane = tid & 63;
    const int l16  = lane & 15;
    const int quad = lane >> 4;
    const int wr   = wave >> 2;       // 0..1  (m-direction wave)
    const int wc   = wave & 3;        // 0..3  (n-direction wave)

    // m-tile-fast linear id + bijective XCD-chunked swizzle (nwg % 8 == 0)
    int id = blockIdx.y * gridDim.x + blockIdx.x;
    const int nwg = gridDim.x * gridDim.y;
    if ((nwg & 7) == 0) {
        const int q = nwg >> 3;
        id = (id & 7) * q + (id >> 3);
    }
    const int m0 = (id % gridDim.x) * 256;
    const int n0 = (id / gridDim.x) * 256;

    const int NT = K >> 6;            // K-tiles of 64

    // ---- staging address precompute (per thread: 2 chunks per unit) -------
    const int l8  = lane >> 3;
    const int gc8 = ((lane & 7) ^ l8) * 8;   // swizzled k-chunk (elements)
    int aoff[2][2], boff[2][2];              // [p][mq / nq] element offsets
    #pragma unroll
    for (int p = 0; p < 2; ++p) {
        const int W  = wave * 2 + p;         // 0..15
        const int rs = W * 8 + l8;           // rowslot 0..127  (rs&7 == l8)
        #pragma unroll
        for (int mq = 0; mq < 2; ++mq) {
            const int m = (rs >> 6) * 128 + mq * 64 + (rs & 63);
            aoff[p][mq] = (m0 + m) * lda + gc8;
        }
        #pragma unroll
        for (int nq = 0; nq < 2; ++nq) {
            int n = n0 + (rs >> 5) * 64 + nq * 32 + (rs & 31);
            n = n < N ? n : N - 1;           // N-edge clamp (masked in epi)
            boff[p][nq] = n * ldb + gc8;
        }
    }
    const int W0 = wave * 2, W1 = W0 + 1;

    auto stageA = [&](int kt, int mq) {
        const int ko = (kt < NT ? kt : NT - 1) << 6;   // clamp tail prefetch
        __bf16* d = &sA[kt & 1][mq][0];
        gl_lds16(A + aoff[0][mq] + ko, d + W0 * 512);
        gl_lds16(A + aoff[1][mq] + ko, d + W1 * 512);
    };
    auto stageB = [&](int kt, int nq) {
        const int ko = (kt < NT ? kt : NT - 1) << 6;
        __bf16* d = &sB[kt & 1][nq][0];
        gl_lds16(Bt + boff[0][nq] + ko, d + W0 * 512);
        gl_lds16(Bt + boff[1][nq] + ko, d + W1 * 512);
    };

    // fragment read k-offsets (swizzled): col8 = ks*4+quad, XOR rowslot&7=l16&7
    const int kx0 = ((0 + quad) ^ (l16 & 7)) * 8;
    const int kx1 = ((4 + quad) ^ (l16 & 7)) * 8;

    f4_t  acc[8][4] = {};
    bf8_t af[4][2], b0[2][2], b1[2][2];

    // ---- prologue: A0[0] B0[0] A1[0] B1[0] A0[1] B0[1]  (12 loads/wave) ----
    stageA(0, 0); stageB(0, 0); stageA(0, 1); stageB(0, 1);
    stageA(1, 0); stageB(1, 0);
    asm volatile("s_waitcnt vmcnt(8)" ::: "memory");   // A0[0],B0[0] landed
    phase_bar();

    // ---- main loop --------------------------------------------------------
    for (int V = 0; V < NT; ++V) {
        const int c = V & 1;
        const __bf16* a0p = &sA[c][0][0];
        const __bf16* a1p = &sA[c][1][0];
        const __bf16* bp0 = &sB[c][0][0];
        const __bf16* bp1 = &sB[c][1][0];

        // phase 1: quadrant (mq0, nq0); stage A1[V+1]
        READ_AQ(a0p)
        READ_BQ(bp0, b0)
        stageA(V + 1, 1);
        phase_bar();
        __builtin_amdgcn_s_setprio(1);
        MFMA_QUAD(0, 0, b0)
        __builtin_amdgcn_s_setprio(0);
        asm volatile("s_waitcnt vmcnt(6)" ::: "memory");   // B1[V] landed
        phase_bar();

        // phase 2: quadrant (mq0, nq1); stage B1[V+1]
        READ_BQ(bp1, b1)
        stageB(V + 1, 1);
        phase_bar();
        __builtin_amdgcn_s_setprio(1);
        MFMA_QUAD(0, 2, b1)
        __builtin_amdgcn_s_setprio(0);
        phase_bar();

        // phase 3: quadrant (mq1, nq0); stage A0[V+2]
        READ_AQ(a1p)
        stageA(V + 2, 0);
        phase_bar();
        __builtin_amdgcn_s_setprio(1);
        MFMA_QUAD(4, 0, b0)
        __builtin_amdgcn_s_setprio(0);
        phase_bar();

        // phase 4: quadrant (mq1, nq1); stage B0[V+2]
        stageB(V + 2, 0);
        phase_bar();
        __builtin_amdgcn_s_setprio(1);
        MFMA_QUAD(4, 2, b1)
        __builtin_amdgcn_s_setprio(0);
        asm volatile("s_waitcnt vmcnt(8)" ::: "memory");   // A0/B0[V+1] landed
        phase_bar();
    }

    // ---- epilogue: col=lane&15, row=quad*4+reg (verified layout) -----------
    #pragma unroll
    for (int i = 0; i < 8; ++i) {
        const int rbase = m0 + wr * 128 + i * 16 + quad * 4;
        #pragma unroll
        for (int j = 0; j < 4; ++j) {
            const int col = n0 + wc * 64 + j * 16 + l16;
            if (col >= N) continue;
            const float bias = aux[col];
            #pragma unroll
            for (int r = 0; r < 4; ++r)
                C[(long)(rbase + r) * ldc + col] = acc[i][j][r] + bias;
        }
    }
}

// ---------------------------------------------------------------------------
__global__ void gather_cast_k(const int* __restrict__ ids,
                              const float* __restrict__ emb,
                              __bf16* __restrict__ x)
{
    const int g = blockIdx.x;                       // 0..4095 token
    const long row = (long)ids[g] * 1024;
    f4_t v = ((const f4_t*)(emb + row))[threadIdx.x];
    bf4_t o; o[0]=(__bf16)v[0]; o[1]=(__bf16)v[1]; o[2]=(__bf16)v[2]; o[3]=(__bf16)v[3];
    *(bf4_t*)(x + (long)g * 1024 + threadIdx.x * 4) = o;
}

__global__ void cast_k(const float* __restrict__ w, __bf16* __restrict__ o, long n)
{
    long i = ((long)blockIdx.x * 256 + threadIdx.x) * 4;
    if (i >= n) return;
    f4_t v = *(const f4_t*)(w + i);
    bf4_t b; b[0]=(__bf16)v[0]; b[1]=(__bf16)v[1]; b[2]=(__bf16)v[2]; b[3]=(__bf16)v[3];
    *(bf4_t*)(o + i) = b;
}

__global__ void ksum_k(const __bf16* __restrict__ Kt, float* __restrict__ Ksum)
{
    const int d = blockIdx.x, b = blockIdx.y, t = threadIdx.x;
    const __bf16* rowp = Kt + (long)d * 4096 + b * 2048;
    float s = 0.f;
    for (int i = t; i < 2048; i += 256) s += (float)rowp[i];
    __shared__ float red[256];
    red[t] = s; __syncthreads();
    for (int o = 128; o > 0; o >>= 1) { if (t < o) red[t] += red[t + o]; __syncthreads(); }
    if (t == 0) Ksum[b * 1024 + d] = red[0] + 1e-6f;
}

__global__ void z_k(const __bf16* __restrict__ Q, const float* __restrict__ Ksum,
                    float* __restrict__ Z)
{
    const int n = blockIdx.x, b = blockIdx.y, t = threadIdx.x;
    const __bf16* q = Q + ((long)b * 2048 + n) * 1024;
    const float* ks = Ksum + b * 1024;
    float s = 0.f;
    for (int d = t; d < 1024; d += 256) s += (float)q[d] * ks[d];
    __shared__ float red[256];
    red[t] = s; __syncthreads();
    for (int o = 128; o > 0; o >>= 1) { if (t < o) red[t] += red[t + o]; __syncthreads(); }
    if (t == 0) Z[b * 2048 + n] = red[0];
}

__global__ void pooled_k(const __bf16* __restrict__ x, float* __restrict__ out)
{
    const int b = blockIdx.x, d = threadIdx.x;   // 1024 threads
    out[b * 1024 + d] = (float)x[((long)b * 2048 + 2047) * 1024 + d];
}

// ---------------------------------------------------------------------------
static void launch_gemm(int epi, dim3 grid, hipStream_t s,
                        const __bf16* A, long lda, long zsA,
                        const __bf16* B, long ldb, long zsB,
                        void* C, long ldc, long zsC,
                        int M, int N, int K, const float* aux, long zsAux)
{
    dim3 blk(256);
    switch (epi) {
    case EPI_NONE:     hipLaunchKernelGGL((gemm_bt<EPI_NONE>),     grid, blk, 0, s, A,lda,zsA,B,ldb,zsB,C,ldc,zsC,M,N,K,aux,zsAux); break;
    case EPI_BCOL:     hipLaunchKernelGGL((gemm_bt<EPI_BCOL>),     grid, blk, 0, s, A,lda,zsA,B,ldb,zsB,C,ldc,zsC,M,N,K,aux,zsAux); break;
    case EPI_BCOL_ELU: hipLaunchKernelGGL((gemm_bt<EPI_BCOL_ELU>), grid, blk, 0, s, A,lda,zsA,B,ldb,zsB,C,ldc,zsC,M,N,K,aux,zsAux); break;
    case EPI_BROW:     hipLaunchKernelGGL((gemm_bt<EPI_BROW>),     grid, blk, 0, s, A,lda,zsA,B,ldb,zsB,C,ldc,zsC,M,N,K,aux,zsAux); break;
    case EPI_BROW_ELU: hipLaunchKernelGGL((gemm_bt<EPI_BROW_ELU>), grid, blk, 0, s, A,lda,zsA,B,ldb,zsB,C,ldc,zsC,M,N,K,aux,zsAux); break;
    case EPI_ZDIV:     hipLaunchKernelGGL((gemm_bt<EPI_ZDIV>),     grid, blk, 0, s, A,lda,zsA,B,ldb,zsB,C,ldc,zsC,M,N,K,aux,zsAux); break;
    case EPI_BCOL_F32: hipLaunchKernelGGL((gemm_bt<EPI_BCOL_F32>), grid, blk, 0, s, A,lda,zsA,B,ldb,zsB,C,ldc,zsC,M,N,K,aux,zsAux); break;
    }
}

extern "C" void kernel_launch(void* const* d_in, const int* in_sizes, int n_in,
                              void* d_out, int out_size, void* d_ws, size_t ws_size,
                              hipStream_t stream)
{
    const int*   ids = (const int*)  d_in[0];
    const float* emb = (const float*)d_in[1];
    const float* Wq  = (const float*)d_in[2];
    const float* bq  = (const float*)d_in[3];
    const float* Wk  = (const float*)d_in[4];
    const float* bk  = (const float*)d_in[5];
    const float* Wv  = (const float*)d_in[6];
    const float* bv  = (const float*)d_in[7];
    const float* Wo  = (const float*)d_in[8];
    const float* bo  = (const float*)d_in[9];
    const float* Wh  = (const float*)d_in[10];
    const float* bh  = (const float*)d_in[11];
    float* out = (float*)d_out;

    // workspace carve-up (bf16 elements); total ~158 MB
    __bf16* x_bf   = (__bf16*)d_ws;             // (4096,1024)  x (reused as x_next)
    __bf16* Q_bf   = x_bf   + 4194304;          // (4096,1024)
    __bf16* Kt_bf  = Q_bf   + 4194304;          // (1024,4096)  K^T, batches side by side
    __bf16* Vt_bf  = Kt_bf  + 4194304;          // (1024,4096)
    __bf16* KVt_bf = Vt_bf  + 4194304;          // 2 x (1024,1024)  (KV)^T per batch
    __bf16* ctx_bf = KVt_bf + 2097152;          // (4096,1024)
    __bf16* Wq_bf  = ctx_bf + 4194304;          // (2,1024,1024)
    __bf16* Wk_bf  = Wq_bf  + 2097152;
    __bf16* Wv_bf  = Wk_bf  + 2097152;
    __bf16* Wo_bf  = Wv_bf  + 2097152;
    __bf16* Wh_bf  = Wo_bf  + 2097152;          // (50257,1024)
    float*  Ksum   = (float*)(Wh_bf + 51463168);// (2,1024)  includes +EPS
    float*  Z      = Ksum + 2048;               // (2,2048)

    auto castn = [&](const float* src, __bf16* dst, long n) {
        int blocks = (int)((n / 4 + 255) / 256);
        hipLaunchKernelGGL(cast_k, dim3(blocks), dim3(256), 0, stream, src, dst, n);
    };
    castn(Wq, Wq_bf, 2097152);
    castn(Wk, Wk_bf, 2097152);
    castn(Wv, Wv_bf, 2097152);
    castn(Wo, Wo_bf, 2097152);
    castn(Wh, Wh_bf, 51463168);
    hipLaunchKernelGGL(gather_cast_k, dim3(4096), dim3(256), 0, stream, ids, emb, x_bf);

    for (int l = 0; l < 2; ++l) {
        const __bf16 *wq = Wq_bf + l * 1048576, *wk = Wk_bf + l * 1048576,
                     *wv = Wv_bf + l * 1048576, *wo = Wo_bf + l * 1048576;
        const float *bql = bq + l * 1024, *bkl = bk + l * 1024,
                    *bvl = bv + l * 1024, *bol = bo + l * 1024;

        // Q = elu(x Wq^T + bq)+1                    (4096,1024)
        launch_gemm(EPI_BCOL_ELU, dim3(8, 32, 1), stream,
                    x_bf, 1024, 0, wq, 1024, 0, Q_bf, 1024, 0,
                    4096, 1024, 1024, bql, 0);
        // Kt = (elu(x Wk^T + bk)+1)^T  => gemm(Wk, x) with per-row bias   (1024,4096)
        launch_gemm(EPI_BROW_ELU, dim3(32, 8, 1), stream,
                    wk, 1024, 0, x_bf, 1024, 0, Kt_bf, 4096, 0,
                    1024, 4096, 1024, bkl, 0);
        // Vt = (x Wv^T + bv)^T                      (1024,4096)
        launch_gemm(EPI_BROW, dim3(32, 8, 1), stream,
                    wv, 1024, 0, x_bf, 1024, 0, Vt_bf, 4096, 0,
                    1024, 4096, 1024, bvl, 0);
        // Ksum[b,d] = sum_n K + EPS
        hipLaunchKernelGGL(ksum_k, dim3(1024, 2), dim3(256), 0, stream, Kt_bf, Ksum);
        // KVt_b[e,d] = sum_n V[n,e] K[n,d]          2 x (1024,1024)
        launch_gemm(EPI_NONE, dim3(8, 8, 2), stream,
                    Vt_bf, 4096, 2048, Kt_bf, 4096, 2048, KVt_bf, 1024, 1048576,
                    1024, 1024, 2048, Ksum, 0);
        // Z[b,n] = Q . Ksum
        hipLaunchKernelGGL(z_k, dim3(2048, 2), dim3(256), 0, stream, Q_bf, Ksum, Z);
        // ctx = (Q @ KV) / Z                        2 x (2048,1024)
        launch_gemm(EPI_ZDIV, dim3(8, 16, 2), stream,
                    Q_bf, 1024, 2097152, KVt_bf, 1024, 1048576, ctx_bf, 1024, 2097152,
                    2048, 1024, 1024, Z, 2048);
        // x = ctx Wo^T + bo                          (4096,1024) -> overwrite x_bf
        launch_gemm(EPI_BCOL, dim3(8, 32, 1), stream,
                    ctx_bf, 1024, 0, wo, 1024, 0, x_bf, 1024, 0,
                    4096, 1024, 1024, bol, 0);
    }

    // logits = x W_head^T + b_head -> fp32 d_out    (4096,50257)
    // 256^2-tile 8-wave pipelined kernel: grid (M/256=16, ceil(N/256)=197)
    hipLaunchKernelGGL(gemm256_head, dim3(16, 197), dim3(512), 0, stream,
                       x_bf, 1024, Wh_bf, 1024, out, 50257,
                       4096, 50257, 1024, bh);
    // pooled = x[:, -1]
    hipLaunchKernelGGL(pooled_k, dim3(2), dim3(1024), 0, stream,
                       x_bf, out + (long)4096 * 50257);
}